// Round 10
// baseline (251.872 us; speedup 1.0000x reference)
//
#include <hip/hip_runtime.h>
#include <hip/hip_fp16.h>

// SparseEncoder4D: gather-GEMM-scatter sparse conv (1->8->8->1) + dense scatter.
// R16 post-mortem: replacing memset+k_h1b (suspected ~100 us) moved total
// -3.5 us -> they were ~15 us each all along. ~100 us of the 204 is invariant
// and unaccounted; suspect fixed harness cost, unprovable while top-5 is
// saturated by five ~49 us k_h2m instances.
// R17: DECOMPOSITION ROUND. Split k_h2m into two half-range dispatches
// (~23 us each) -> top-5 cutoff drops to ~23 us; any hidden kernel >=24 us
// must surface. Piggyback: sentinel-select gathers (best-ever 46.5 us config;
// broadcast line coalesces, no per-iter branch) + nt-hint on gathers (random
// table, L1 retention worthless) + single-shot k_zero grid.
// Predict: halves 22-24 us, total 198-206. If top-5 still all k_h2m halves ->
// remaining block is harness-fixed -> coop-fuse gaps or declare floor.
// NOTE: assumes n_total >= 64 and n_total % 16 == 0 (holds: 150000).

#define KK 81
#define CH 8
#define NS 21     // K-slices of 32 for k_h2m: ceil(648/32)
#define TT 4
#define ZZ 32
#define YY 256
#define XX 256

typedef __attribute__((ext_vector_type(8))) _Float16 half8;  // 16 B
typedef __attribute__((ext_vector_type(4))) float f32x4;

__device__ __forceinline__ int cell_of(const int* coords, const int* batch, int n) {
    int4 c = *(const int4*)(coords + 4 * n);  // (x, y, z, t)
    int b = batch[n];
    return (((b * TT + c.w) * ZZ + c.z) * YY + c.y) * XX + c.x;
}

// ---------------- k_zero: grid zero + W1tab build + sentinel ----------------
// Exact cover: 16384 blocks x 256 thr x 1 float4 = 16,777,216 floats.
// W1tab[s*64+l] = B-fragment of w1 for slice s (K=32s+8(l>>4)+j), col d=l&15.
__global__ __launch_bounds__(256) void k_zero(float4* __restrict__ dst, int n4,
                                              const float* __restrict__ w1,
                                              half8* __restrict__ W1tab,
                                              half8* __restrict__ h1, int n_total) {
    const int tid = threadIdx.x;
    if (blockIdx.x == 0) {
        if (tid < 192) {
            int s = tid >> 6, l = tid & 63, qb = (l >> 4) & 3, d = l & 15;
            half8 b;
#pragma unroll
            for (int j = 0; j < 8; j++) {
                int k = 32 * s + 8 * qb + j;
                b[j] = (k < KK && d < CH) ? (_Float16)w1[k * CH + d] : (_Float16)0.f;
            }
            W1tab[s * 64 + l] = b;
        }
        if (tid == 0) {
            half8 z;
#pragma unroll
            for (int c = 0; c < CH; c++) z[c] = (_Float16)0.f;
            h1[n_total] = z;  // sentinel row for masked gather slots
        }
    }
    float4 zz = {0.f, 0.f, 0.f, 0.f};
    int i = blockIdx.x * 256 + tid;
    if (i < n4) dst[i] = zz;
}

// ---------------- layer 1 as mask-GEMM MFMA + scat_max fusion ---------------
// (unchanged from R16 -- verified correct, est. ~15 us)
__global__ __launch_bounds__(256) void k_h1b(const half8* __restrict__ W1tab,
                                             const float* __restrict__ w2,
                                             const int* __restrict__ nbr_mask,
                                             const int* __restrict__ coords,
                                             const int* __restrict__ batch,
                                             half8* __restrict__ h1,
                                             uint4* __restrict__ bits4,
                                             half8* __restrict__ Btab8,
                                             int* __restrict__ dsti, int n_total) {
    __shared__ int sm[5200];   // 64*81 = 5184 + pad (20.8 KB)
    const int tid = threadIdx.x;
    const int lane = tid & 63, wid = tid >> 6;
    const int m = lane & 15, q = lane >> 4;
    const int n0 = blockIdx.x * 64;
    int wb = n0;
    if (wb + 64 > n_total) wb = n_total - 64;   // overlap tail; rewrites identical

    // fused scat_max: issue early, latency hides under staging
    if (tid < 64) atomicMax(dsti + cell_of(coords, batch, wb + tid), wb + tid + 1);

    if (blockIdx.x < NS && tid < 32) {   // build compact Btab8 (d<8 only)
        int s = blockIdx.x, qb = tid >> 3, d = tid & 7;
        int kk = 4 * s + qb;
        half8 b;
#pragma unroll
        for (int j = 0; j < CH; j++)
            b[j] = (kk < KK) ? (_Float16)w2[(kk * CH + j) * CH + d]
                             : (_Float16)0.f;
        Btab8[s * 32 + tid] = b;
    }

    // stage 5184 contiguous mask ints = 1296 int4 (wb*81 is 16B-aligned)
    const int4* msrc = (const int4*)(nbr_mask + (size_t)wb * KK);
#pragma unroll
    for (int j = 0; j < 6; j++) {
        int i = tid + j * 256;
        if (i < 1296) ((int4*)sm)[i] = msrc[i];
    }
    __syncthreads();

    const int lr = wid * 16 + m;
    f32x4 acc = {0.f, 0.f, 0.f, 0.f};
    unsigned wv[3];
#pragma unroll
    for (int s = 0; s < 3; s++) {
        const int base = lr * KK + 32 * s + 8 * q;   // max 5198 < 5200
        int mm[8];
#pragma unroll
        for (int j = 0; j < 8; j++) mm[j] = sm[base + j] & 1;
        unsigned byte = 0;
#pragma unroll
        for (int j = 0; j < 8; j++) byte |= (unsigned)mm[j] << j;
        if (s == 2) byte &= (q < 2) ? 0xFFu : (q == 2 ? 0x1u : 0x0u);  // k>80 off
        union { unsigned u[4]; half8 h; } ua;
#pragma unroll
        for (int jj = 0; jj < 4; jj++)
            ua.u[jj] = (unsigned)mm[2 * jj] * 0x3C00u |
                       ((unsigned)mm[2 * jj + 1] * 0x3C00u << 16);
        half8 bfrag = W1tab[s * 64 + lane];          // L1-hot 3 KB
        acc = __builtin_amdgcn_mfma_f32_16x16x32_f16(ua.h, bfrag, acc, 0, 0, 0);
        unsigned v = byte << (8 * q);
        v |= __shfl_xor(v, 16);                      // OR across the 4 q-lanes
        v |= __shfl_xor(v, 32);
        wv[s] = v;
    }
    wv[2] &= 0x1FFFFu;   // bits 64..80 only

    if (q == 0) {        // lanes 0..15: one uint4 per row, contiguous 256 B
        uint4 bwout; bwout.x = wv[0]; bwout.y = wv[1]; bwout.z = wv[2]; bwout.w = 0u;
        bits4[wb + wid * 16 + m] = bwout;
    }

    // D layout: col = lane&15 (=channel), row = q*4 + reg (=local row).
    if (m < CH) {
        _Float16* hp = (_Float16*)h1;
#pragma unroll
        for (int r = 0; r < 4; r++) {
            float f = fmaxf(acc[r], 0.f);
            hp[(size_t)(wb + wid * 16 + q * 4 + r) * CH + m] = (_Float16)f;
        }
    }
}

// ---------------- layer 2 + head: MFMA gather-GEMM (half-range) -------------
// Split into two dispatches via row0 to lower the profiler's top-5 cutoff.
// Sentinel-select gathers: ix = bit ? idx : n_total (zero row); broadcast
// line coalesces so request count ~= active lanes. nt-hint: random 2.4 MB
// table has ~1% L1 hit rate -> retention worthless.
__global__ __launch_bounds__(256, 4) void k_h2m(const half8* __restrict__ h1,
                                                const half8* __restrict__ Btab8,
                                                const int* __restrict__ nbr_idx,
                                                const uint4* __restrict__ bits4,
                                                const float* __restrict__ w_out,
                                                float* __restrict__ outf,
                                                int n_total, int row0) {
    __shared__ int4 sB8[NS * 32];       // 10752 B compact Btab
    __shared__ int  sidx[4 * 1300];     // 4 waves x (1296 idx + pad) = 20800 B
    const int tid = threadIdx.x;
    const int lane = tid & 63, wid = tid >> 6;
    const int m = lane & 15, q = lane >> 4;

    const int rw = row0 + blockIdx.x * 64 + (wid << 4);  // wave's first row
    int wb = rw;
    if (wb + 16 > n_total) wb = n_total - 16;          // clamp (N%16==0)

    // stage wave's 16 idx rows: 5184 contiguous bytes = 324 int4
    {
        int4* dst = (int4*)(sidx + wid * 1300);
        const int4* gsrc = (const int4*)(nbr_idx + (size_t)wb * KK);
#pragma unroll
        for (int j = 0; j < 6; j++) {
            int li = lane + j * 64;
            if (li < 324) dst[li] = gsrc[li];
        }
    }
    // stage compact Btab8: 672 int4, block-wide
    {
        const int4* gB = (const int4*)Btab8;
#pragma unroll
        for (int j = 0; j < 3; j++) {
            int i = tid + j * 256;
            if (i < NS * 32) sB8[i] = gB[i];
        }
    }
    __syncthreads();

    const int rowc = wb + m;
    const uint4 bw = bits4[rowc];
    const int* mi = sidx + wid * 1300 + m * KK + q;    // [4s] per slice

    f32x4 acc0 = {0.f, 0.f, 0.f, 0.f};
    f32x4 acc1 = {0.f, 0.f, 0.f, 0.f};
#pragma unroll
    for (int s = 0; s < NS; s++) {
        const unsigned word = (s < 8) ? bw.x : (s < 16) ? bw.y : bw.z;
        const unsigned bit = (word >> ((4 * s + q) & 31)) & 1u;
        // s==20, q>=1 reads pad garbage; bit==0 there (bits 81+ zero) ->
        // sentinel row selected. No OOB: 1298 < 1300.
        const unsigned ixr = (unsigned)mi[4 * s];      // ds_read_b32, imm offset
        const unsigned ix = bit ? ixr : (unsigned)n_total;  // cndmask, no branch
        half8 a = __builtin_nontemporal_load(h1 + ix); // 16 B gather = A-frag
        half8 b = {(_Float16)0.f, (_Float16)0.f, (_Float16)0.f, (_Float16)0.f,
                   (_Float16)0.f, (_Float16)0.f, (_Float16)0.f, (_Float16)0.f};
        if (m < CH) b = *(const half8*)&sB8[s * 32 + q * 8 + m];  // ds_read_b128
        if (s & 1) acc1 = __builtin_amdgcn_mfma_f32_16x16x32_f16(a, b, acc1, 0, 0, 0);
        else       acc0 = __builtin_amdgcn_mfma_f32_16x16x32_f16(a, b, acc0, 0, 0, 0);
    }
    f32x4 acc = acc0 + acc1;

    float wo = (m < CH) ? w_out[m] : 0.f;
    float v0 = fmaxf(acc[0], 0.f) * wo, v1 = fmaxf(acc[1], 0.f) * wo;
    float v2 = fmaxf(acc[2], 0.f) * wo, v3 = fmaxf(acc[3], 0.f) * wo;
#pragma unroll
    for (int off = 1; off < 16; off <<= 1) {
        v0 += __shfl_xor(v0, off, 16);
        v1 += __shfl_xor(v1, off, 16);
        v2 += __shfl_xor(v2, off, 16);
        v3 += __shfl_xor(v3, off, 16);
    }
    if (m == 0) {
        int gn = rw + q * 4;   // tail-wave rows (wb!=rw) -> gn >= n_total -> no-op
        if (gn + 0 < n_total) outf[gn + 0] = v0;
        if (gn + 1 < n_total) outf[gn + 1] = v1;
        if (gn + 2 < n_total) outf[gn + 2] = v2;
        if (gn + 3 < n_total) outf[gn + 3] = v3;
    }
}

// ---------------- deterministic dense scatter (write phase) -----------------
__global__ __launch_bounds__(256) void k_scat_write(const int* __restrict__ coords,
                                                    const int* __restrict__ batch,
                                                    const float* __restrict__ outf,
                                                    int* dsti, float* dstf, int n_total) {
    int n = blockIdx.x * blockDim.x + threadIdx.x;
    if (n >= n_total) return;
    int cell = cell_of(coords, batch, n);
    if (dsti[cell] == n + 1) dstf[cell] = outf[n];
}

extern "C" void kernel_launch(void* const* d_in, const int* in_sizes, int n_in,
                              void* d_out, int out_size, void* d_ws, size_t ws_size,
                              hipStream_t stream) {
    const float* w1       = (const float*)d_in[1];
    const float* w2       = (const float*)d_in[2];
    const float* w_out    = (const float*)d_in[3];
    const int*   nbr_idx  = (const int*)d_in[4];
    const int*   nbr_mask = (const int*)d_in[5];
    const int*   coords   = (const int*)d_in[6];
    const int*   batch    = (const int*)d_in[7];

    int n_total = in_sizes[0];

    // ws: h1 (N+1 fp16x8) | bits4 (N uint4) | outf (N f32) | Btab8 | W1tab
    half8* h1    = (half8*)d_ws;
    uint4* bits4 = (uint4*)((char*)d_ws + (size_t)(n_total + 1) * sizeof(half8));
    float* outf  = (float*)((char*)bits4 + (size_t)n_total * sizeof(uint4));
    half8* Btab8 = (half8*)(outf + n_total);
    half8* W1tab = Btab8 + NS * 32;
    float* out   = (float*)d_out;

    int n4 = out_size / 4;                 // 4,194,304 float4
    int nbz = (n4 + 255) / 256;            // 16384 exact
    k_zero<<<nbz, 256, 0, stream>>>((float4*)out, n4, w1, W1tab, h1, n_total);

    int nb1 = (n_total + 63) / 64;         // 2344 row-groups
    k_h1b<<<nb1, 256, 0, stream>>>(W1tab, w2, nbr_mask, coords, batch,
                                   h1, bits4, Btab8, (int*)out, n_total);

    int ga = nb1 / 2, gb = nb1 - ga;       // split k_h2m for profiler visibility
    k_h2m<<<ga, 256, 0, stream>>>(h1, Btab8, nbr_idx, bits4, w_out, outf,
                                  n_total, 0);
    k_h2m<<<gb, 256, 0, stream>>>(h1, Btab8, nbr_idx, bits4, w_out, outf,
                                  n_total, ga * 64);

    int nb = (n_total + 255) / 256;
    k_scat_write<<<nb, 256, 0, stream>>>(coords, batch, outf, (int*)out, out, n_total);
}

// Round 11
// 205.861 us; speedup vs baseline: 1.2235x; 1.2235x over previous
//
#include <hip/hip_runtime.h>
#include <hip/hip_fp16.h>

// SparseEncoder4D: gather-GEMM-scatter sparse conv (1->8->8->1) + dense scatter.
// R17 post-mortem: __builtin_nontemporal_load on the h1 gather set the nt
// cache flag -> defeated L2 retention of the 2.4 MB h1 table -> 6.1M gathers
// went to HBM (FETCH 41 -> 170 MB, k_h2m 49.5 -> 100 us total). Split itself
// cost ~0 (dispatch overhead negligible, consistent with R13's ~5 us/disp).
// R18: revert nt (plain L2-cached gather). Keep the half-split (top-5 cutoff
// ~24 us -> hidden kernels must surface) and sentinel-select gathers (clean
// A/B vs R14's exec-mask at the same 45% occupancy structure).
// Predict halves 23-26 us each, FETCH ~21 MB/half, total ~200-205.
// NOTE: assumes n_total >= 64 and n_total % 16 == 0 (holds: 150000).

#define KK 81
#define CH 8
#define NS 21     // K-slices of 32 for k_h2m: ceil(648/32)
#define TT 4
#define ZZ 32
#define YY 256
#define XX 256

typedef __attribute__((ext_vector_type(8))) _Float16 half8;  // 16 B
typedef __attribute__((ext_vector_type(4))) float f32x4;

__device__ __forceinline__ int cell_of(const int* coords, const int* batch, int n) {
    int4 c = *(const int4*)(coords + 4 * n);  // (x, y, z, t)
    int b = batch[n];
    return (((b * TT + c.w) * ZZ + c.z) * YY + c.y) * XX + c.x;
}

// ---------------- k_zero: grid zero + W1tab build + sentinel ----------------
// Exact cover: 16384 blocks x 256 thr x 1 float4 = 16,777,216 floats.
// W1tab[s*64+l] = B-fragment of w1 for slice s (K=32s+8(l>>4)+j), col d=l&15.
__global__ __launch_bounds__(256) void k_zero(float4* __restrict__ dst, int n4,
                                              const float* __restrict__ w1,
                                              half8* __restrict__ W1tab,
                                              half8* __restrict__ h1, int n_total) {
    const int tid = threadIdx.x;
    if (blockIdx.x == 0) {
        if (tid < 192) {
            int s = tid >> 6, l = tid & 63, qb = (l >> 4) & 3, d = l & 15;
            half8 b;
#pragma unroll
            for (int j = 0; j < 8; j++) {
                int k = 32 * s + 8 * qb + j;
                b[j] = (k < KK && d < CH) ? (_Float16)w1[k * CH + d] : (_Float16)0.f;
            }
            W1tab[s * 64 + l] = b;
        }
        if (tid == 0) {
            half8 z;
#pragma unroll
            for (int c = 0; c < CH; c++) z[c] = (_Float16)0.f;
            h1[n_total] = z;  // sentinel row for masked gather slots
        }
    }
    float4 zz = {0.f, 0.f, 0.f, 0.f};
    int i = blockIdx.x * 256 + tid;
    if (i < n4) dst[i] = zz;
}

// ---------------- layer 1 as mask-GEMM MFMA + scat_max fusion ---------------
// (unchanged from R16 -- verified correct)
__global__ __launch_bounds__(256) void k_h1b(const half8* __restrict__ W1tab,
                                             const float* __restrict__ w2,
                                             const int* __restrict__ nbr_mask,
                                             const int* __restrict__ coords,
                                             const int* __restrict__ batch,
                                             half8* __restrict__ h1,
                                             uint4* __restrict__ bits4,
                                             half8* __restrict__ Btab8,
                                             int* __restrict__ dsti, int n_total) {
    __shared__ int sm[5200];   // 64*81 = 5184 + pad (20.8 KB)
    const int tid = threadIdx.x;
    const int lane = tid & 63, wid = tid >> 6;
    const int m = lane & 15, q = lane >> 4;
    const int n0 = blockIdx.x * 64;
    int wb = n0;
    if (wb + 64 > n_total) wb = n_total - 64;   // overlap tail; rewrites identical

    // fused scat_max: issue early, latency hides under staging
    if (tid < 64) atomicMax(dsti + cell_of(coords, batch, wb + tid), wb + tid + 1);

    if (blockIdx.x < NS && tid < 32) {   // build compact Btab8 (d<8 only)
        int s = blockIdx.x, qb = tid >> 3, d = tid & 7;
        int kk = 4 * s + qb;
        half8 b;
#pragma unroll
        for (int j = 0; j < CH; j++)
            b[j] = (kk < KK) ? (_Float16)w2[(kk * CH + j) * CH + d]
                             : (_Float16)0.f;
        Btab8[s * 32 + tid] = b;
    }

    // stage 5184 contiguous mask ints = 1296 int4 (wb*81 is 16B-aligned)
    const int4* msrc = (const int4*)(nbr_mask + (size_t)wb * KK);
#pragma unroll
    for (int j = 0; j < 6; j++) {
        int i = tid + j * 256;
        if (i < 1296) ((int4*)sm)[i] = msrc[i];
    }
    __syncthreads();

    const int lr = wid * 16 + m;
    f32x4 acc = {0.f, 0.f, 0.f, 0.f};
    unsigned wv[3];
#pragma unroll
    for (int s = 0; s < 3; s++) {
        const int base = lr * KK + 32 * s + 8 * q;   // max 5198 < 5200
        int mm[8];
#pragma unroll
        for (int j = 0; j < 8; j++) mm[j] = sm[base + j] & 1;
        unsigned byte = 0;
#pragma unroll
        for (int j = 0; j < 8; j++) byte |= (unsigned)mm[j] << j;
        if (s == 2) byte &= (q < 2) ? 0xFFu : (q == 2 ? 0x1u : 0x0u);  // k>80 off
        union { unsigned u[4]; half8 h; } ua;
#pragma unroll
        for (int jj = 0; jj < 4; jj++)
            ua.u[jj] = (unsigned)mm[2 * jj] * 0x3C00u |
                       ((unsigned)mm[2 * jj + 1] * 0x3C00u << 16);
        half8 bfrag = W1tab[s * 64 + lane];          // L1-hot 3 KB
        acc = __builtin_amdgcn_mfma_f32_16x16x32_f16(ua.h, bfrag, acc, 0, 0, 0);
        unsigned v = byte << (8 * q);
        v |= __shfl_xor(v, 16);                      // OR across the 4 q-lanes
        v |= __shfl_xor(v, 32);
        wv[s] = v;
    }
    wv[2] &= 0x1FFFFu;   // bits 64..80 only

    if (q == 0) {        // lanes 0..15: one uint4 per row, contiguous 256 B
        uint4 bwout; bwout.x = wv[0]; bwout.y = wv[1]; bwout.z = wv[2]; bwout.w = 0u;
        bits4[wb + wid * 16 + m] = bwout;
    }

    // D layout: col = lane&15 (=channel), row = q*4 + reg (=local row).
    if (m < CH) {
        _Float16* hp = (_Float16*)h1;
#pragma unroll
        for (int r = 0; r < 4; r++) {
            float f = fmaxf(acc[r], 0.f);
            hp[(size_t)(wb + wid * 16 + q * 4 + r) * CH + m] = (_Float16)f;
        }
    }
}

// ---------------- layer 2 + head: MFMA gather-GEMM (half-range) -------------
// Split into two dispatches via row0 (profiler top-5 cutoff ~24 us).
// Sentinel-select gathers: ix = bit ? idx : n_total (zero row, L1-hot
// broadcast line). Plain cached load -- h1 (2.4 MB) stays L2-resident.
__global__ __launch_bounds__(256, 4) void k_h2m(const half8* __restrict__ h1,
                                                const half8* __restrict__ Btab8,
                                                const int* __restrict__ nbr_idx,
                                                const uint4* __restrict__ bits4,
                                                const float* __restrict__ w_out,
                                                float* __restrict__ outf,
                                                int n_total, int row0) {
    __shared__ int4 sB8[NS * 32];       // 10752 B compact Btab
    __shared__ int  sidx[4 * 1300];     // 4 waves x (1296 idx + pad) = 20800 B
    const int tid = threadIdx.x;
    const int lane = tid & 63, wid = tid >> 6;
    const int m = lane & 15, q = lane >> 4;

    const int rw = row0 + blockIdx.x * 64 + (wid << 4);  // wave's first row
    int wb = rw;
    if (wb + 16 > n_total) wb = n_total - 16;          // clamp (N%16==0)

    // stage wave's 16 idx rows: 5184 contiguous bytes = 324 int4
    {
        int4* dst = (int4*)(sidx + wid * 1300);
        const int4* gsrc = (const int4*)(nbr_idx + (size_t)wb * KK);
#pragma unroll
        for (int j = 0; j < 6; j++) {
            int li = lane + j * 64;
            if (li < 324) dst[li] = gsrc[li];
        }
    }
    // stage compact Btab8: 672 int4, block-wide
    {
        const int4* gB = (const int4*)Btab8;
#pragma unroll
        for (int j = 0; j < 3; j++) {
            int i = tid + j * 256;
            if (i < NS * 32) sB8[i] = gB[i];
        }
    }
    __syncthreads();

    const int rowc = wb + m;
    const uint4 bw = bits4[rowc];
    const int* mi = sidx + wid * 1300 + m * KK + q;    // [4s] per slice

    f32x4 acc0 = {0.f, 0.f, 0.f, 0.f};
    f32x4 acc1 = {0.f, 0.f, 0.f, 0.f};
#pragma unroll
    for (int s = 0; s < NS; s++) {
        const unsigned word = (s < 8) ? bw.x : (s < 16) ? bw.y : bw.z;
        const unsigned bit = (word >> ((4 * s + q) & 31)) & 1u;
        // s==20, q>=1 reads pad garbage; bit==0 there (bits 81+ zero) ->
        // sentinel row selected. No OOB: 1298 < 1300.
        const unsigned ixr = (unsigned)mi[4 * s];      // ds_read_b32, imm offset
        const unsigned ix = bit ? ixr : (unsigned)n_total;  // cndmask, no branch
        half8 a = h1[ix];                              // 16 B gather = A-frag
        half8 b = {(_Float16)0.f, (_Float16)0.f, (_Float16)0.f, (_Float16)0.f,
                   (_Float16)0.f, (_Float16)0.f, (_Float16)0.f, (_Float16)0.f};
        if (m < CH) b = *(const half8*)&sB8[s * 32 + q * 8 + m];  // ds_read_b128
        if (s & 1) acc1 = __builtin_amdgcn_mfma_f32_16x16x32_f16(a, b, acc1, 0, 0, 0);
        else       acc0 = __builtin_amdgcn_mfma_f32_16x16x32_f16(a, b, acc0, 0, 0, 0);
    }
    f32x4 acc = acc0 + acc1;

    float wo = (m < CH) ? w_out[m] : 0.f;
    float v0 = fmaxf(acc[0], 0.f) * wo, v1 = fmaxf(acc[1], 0.f) * wo;
    float v2 = fmaxf(acc[2], 0.f) * wo, v3 = fmaxf(acc[3], 0.f) * wo;
#pragma unroll
    for (int off = 1; off < 16; off <<= 1) {
        v0 += __shfl_xor(v0, off, 16);
        v1 += __shfl_xor(v1, off, 16);
        v2 += __shfl_xor(v2, off, 16);
        v3 += __shfl_xor(v3, off, 16);
    }
    if (m == 0) {
        int gn = rw + q * 4;   // tail-wave rows (wb!=rw) -> gn >= n_total -> no-op
        if (gn + 0 < n_total) outf[gn + 0] = v0;
        if (gn + 1 < n_total) outf[gn + 1] = v1;
        if (gn + 2 < n_total) outf[gn + 2] = v2;
        if (gn + 3 < n_total) outf[gn + 3] = v3;
    }
}

// ---------------- deterministic dense scatter (write phase) -----------------
__global__ __launch_bounds__(256) void k_scat_write(const int* __restrict__ coords,
                                                    const int* __restrict__ batch,
                                                    const float* __restrict__ outf,
                                                    int* dsti, float* dstf, int n_total) {
    int n = blockIdx.x * blockDim.x + threadIdx.x;
    if (n >= n_total) return;
    int cell = cell_of(coords, batch, n);
    if (dsti[cell] == n + 1) dstf[cell] = outf[n];
}

extern "C" void kernel_launch(void* const* d_in, const int* in_sizes, int n_in,
                              void* d_out, int out_size, void* d_ws, size_t ws_size,
                              hipStream_t stream) {
    const float* w1       = (const float*)d_in[1];
    const float* w2       = (const float*)d_in[2];
    const float* w_out    = (const float*)d_in[3];
    const int*   nbr_idx  = (const int*)d_in[4];
    const int*   nbr_mask = (const int*)d_in[5];
    const int*   coords   = (const int*)d_in[6];
    const int*   batch    = (const int*)d_in[7];

    int n_total = in_sizes[0];

    // ws: h1 (N+1 fp16x8) | bits4 (N uint4) | outf (N f32) | Btab8 | W1tab
    half8* h1    = (half8*)d_ws;
    uint4* bits4 = (uint4*)((char*)d_ws + (size_t)(n_total + 1) * sizeof(half8));
    float* outf  = (float*)((char*)bits4 + (size_t)n_total * sizeof(uint4));
    half8* Btab8 = (half8*)(outf + n_total);
    half8* W1tab = Btab8 + NS * 32;
    float* out   = (float*)d_out;

    int n4 = out_size / 4;                 // 4,194,304 float4
    int nbz = (n4 + 255) / 256;            // 16384 exact
    k_zero<<<nbz, 256, 0, stream>>>((float4*)out, n4, w1, W1tab, h1, n_total);

    int nb1 = (n_total + 63) / 64;         // 2344 row-groups
    k_h1b<<<nb1, 256, 0, stream>>>(W1tab, w2, nbr_mask, coords, batch,
                                   h1, bits4, Btab8, (int*)out, n_total);

    int ga = nb1 / 2, gb = nb1 - ga;       // split k_h2m for profiler visibility
    k_h2m<<<ga, 256, 0, stream>>>(h1, Btab8, nbr_idx, bits4, w_out, outf,
                                  n_total, 0);
    k_h2m<<<gb, 256, 0, stream>>>(h1, Btab8, nbr_idx, bits4, w_out, outf,
                                  n_total, ga * 64);

    int nb = (n_total + 255) / 256;
    k_scat_write<<<nb, 256, 0, stream>>>(coords, batch, outf, (int*)out, out, n_total);
}

// Round 13
// 204.518 us; speedup vs baseline: 1.2315x; 1.0066x over previous
//
#include <hip/hip_runtime.h>
#include <hip/hip_fp16.h>

// SparseEncoder4D: gather-GEMM-scatter sparse conv (1->8->8->1) + dense scatter.
// R19 post-mortem: hipLaunchCooperativeKernel is not graph-capturable in this
// harness (absmax == max|ref| -> launch silently failed, output stayed zero).
// Cooperative fusion off the table. R20: revert byte-exact to the measured
// session best (R16 structure, 203.9 us):
//   k_zero (grid-stride float4, builds W1tab + sentinel)
//   k_h1b  (layer-1 as mask-GEMM MFMA, bits pack via shfl, scat_max fused)
//   k_h2m  (layer-2 gather-GEMM MFMA, exec-masked gathers, compact sB8,
//           unsplit; ~46 us == unique-line service wall: 6.07M line reqs
//           x ~4.5cyc / 256 CU ~= 44.5 us, invariant across occupancy/masking)
//   k_scat_write (winner write-back)
// Accounting: ~40.5 us harness ws-poison fill + ~75 us harness reset ops are
// fixed; controllable kernels ~85 us vs ~75 us of BW/line-service floors.
// NOTE: assumes n_total >= 64 and n_total % 16 == 0 (holds: 150000).

#define KK 81
#define CH 8
#define NS 21     // K-slices of 32 for k_h2m: ceil(648/32)
#define TT 4
#define ZZ 32
#define YY 256
#define XX 256

typedef __attribute__((ext_vector_type(8))) _Float16 half8;  // 16 B
typedef __attribute__((ext_vector_type(4))) float f32x4;

__device__ __forceinline__ int cell_of(const int* coords, const int* batch, int n) {
    int4 c = *(const int4*)(coords + 4 * n);  // (x, y, z, t)
    int b = batch[n];
    return (((b * TT + c.w) * ZZ + c.z) * YY + c.y) * XX + c.x;
}

// ---------------- k_zero: grid zero + W1tab build + sentinel ----------------
// W1tab[s*64+l] = B-fragment of w1 for slice s (K=32s+8(l>>4)+j), col d=l&15;
// zero for K>=81 or d>=8.
__global__ __launch_bounds__(256) void k_zero(float4* __restrict__ dst, int n4,
                                              const float* __restrict__ w1,
                                              half8* __restrict__ W1tab,
                                              half8* __restrict__ h1, int n_total) {
    const int tid = threadIdx.x;
    if (blockIdx.x == 0) {
        if (tid < 192) {
            int s = tid >> 6, l = tid & 63, qb = (l >> 4) & 3, d = l & 15;
            half8 b;
#pragma unroll
            for (int j = 0; j < 8; j++) {
                int k = 32 * s + 8 * qb + j;
                b[j] = (k < KK && d < CH) ? (_Float16)w1[k * CH + d] : (_Float16)0.f;
            }
            W1tab[s * 64 + l] = b;
        }
        if (tid == 0) {
            half8 z;
#pragma unroll
            for (int c = 0; c < CH; c++) z[c] = (_Float16)0.f;
            h1[n_total] = z;  // sentinel row (insurance)
        }
    }
    float4 zz = {0.f, 0.f, 0.f, 0.f};
    for (int i = blockIdx.x * 256 + tid; i < n4; i += gridDim.x * 256) dst[i] = zz;
}

// ---------------- layer 1 as mask-GEMM MFMA + scat_max fusion ---------------
// Block = 256 thr = 4 waves, covers 64 rows. Stage 64x81 mask ints (5184
// contiguous) via int4. Lane (m,q): A-frag for row lr=16w+m, K=32s+8q+j from
// staged ints (bit -> fp16 1.0/0.0). 3 MFMAs replace 5184 VALU FMAs. Bits:
// per-slice byte -> word via 2 shfl_xor ORs = 81-bit LE words for k_h2m.
__global__ __launch_bounds__(256) void k_h1b(const half8* __restrict__ W1tab,
                                             const float* __restrict__ w2,
                                             const int* __restrict__ nbr_mask,
                                             const int* __restrict__ coords,
                                             const int* __restrict__ batch,
                                             half8* __restrict__ h1,
                                             uint4* __restrict__ bits4,
                                             half8* __restrict__ Btab8,
                                             int* __restrict__ dsti, int n_total) {
    __shared__ int sm[5200];   // 64*81 = 5184 + pad (20.8 KB)
    const int tid = threadIdx.x;
    const int lane = tid & 63, wid = tid >> 6;
    const int m = lane & 15, q = lane >> 4;
    const int n0 = blockIdx.x * 64;
    int wb = n0;
    if (wb + 64 > n_total) wb = n_total - 64;   // overlap tail; rewrites identical

    // fused scat_max: issue early, latency hides under staging
    if (tid < 64) atomicMax(dsti + cell_of(coords, batch, wb + tid), wb + tid + 1);

    if (blockIdx.x < NS && tid < 32) {   // build compact Btab8 (d<8 only)
        int s = blockIdx.x, qb = tid >> 3, d = tid & 7;
        int kk = 4 * s + qb;
        half8 b;
#pragma unroll
        for (int j = 0; j < CH; j++)
            b[j] = (kk < KK) ? (_Float16)w2[(kk * CH + j) * CH + d]
                             : (_Float16)0.f;
        Btab8[s * 32 + tid] = b;
    }

    // stage 5184 contiguous mask ints = 1296 int4 (wb*81 is 16B-aligned)
    const int4* msrc = (const int4*)(nbr_mask + (size_t)wb * KK);
#pragma unroll
    for (int j = 0; j < 6; j++) {
        int i = tid + j * 256;
        if (i < 1296) ((int4*)sm)[i] = msrc[i];
    }
    __syncthreads();

    const int lr = wid * 16 + m;
    f32x4 acc = {0.f, 0.f, 0.f, 0.f};
    unsigned wv[3];
#pragma unroll
    for (int s = 0; s < 3; s++) {
        const int base = lr * KK + 32 * s + 8 * q;   // max 5198 < 5200
        int mm[8];
#pragma unroll
        for (int j = 0; j < 8; j++) mm[j] = sm[base + j] & 1;
        unsigned byte = 0;
#pragma unroll
        for (int j = 0; j < 8; j++) byte |= (unsigned)mm[j] << j;
        if (s == 2) byte &= (q < 2) ? 0xFFu : (q == 2 ? 0x1u : 0x0u);  // k>80 off
        union { unsigned u[4]; half8 h; } ua;
#pragma unroll
        for (int jj = 0; jj < 4; jj++)
            ua.u[jj] = (unsigned)mm[2 * jj] * 0x3C00u |
                       ((unsigned)mm[2 * jj + 1] * 0x3C00u << 16);
        half8 bfrag = W1tab[s * 64 + lane];          // L1-hot 3 KB
        acc = __builtin_amdgcn_mfma_f32_16x16x32_f16(ua.h, bfrag, acc, 0, 0, 0);
        unsigned v = byte << (8 * q);
        v |= __shfl_xor(v, 16);                      // OR across the 4 q-lanes
        v |= __shfl_xor(v, 32);
        wv[s] = v;
    }
    wv[2] &= 0x1FFFFu;   // bits 64..80 only

    if (q == 0) {        // lanes 0..15: one uint4 per row, contiguous 256 B
        uint4 bwout; bwout.x = wv[0]; bwout.y = wv[1]; bwout.z = wv[2]; bwout.w = 0u;
        bits4[wb + wid * 16 + m] = bwout;
    }

    // D layout: col = lane&15 (=channel), row = q*4 + reg (=local row).
    if (m < CH) {
        _Float16* hp = (_Float16*)h1;
#pragma unroll
        for (int r = 0; r < 4; r++) {
            float f = fmaxf(acc[r], 0.f);
            hp[(size_t)(wb + wid * 16 + q * 4 + r) * CH + m] = (_Float16)f;
        }
    }
}

// ---------------- layer 2 + head: MFMA gather-GEMM --------------------------
// Block = 256 thr = 4 waves; wave owns 16 rows. Wave-private idx staging in
// LDS (contiguous 5184 B via dwordx4), compact Btab8 (10.75 KB) block-shared.
// LDS 31.5 KB -> 5 blocks/CU (~45% occ). Gathers EXEC-MASKED (bit=0 lanes
// issue nothing); h1 (2.4 MB) stays L2-resident. At the unique-line service
// wall (~4.5 cyc/request): further occupancy/masking changes measured neutral.
__global__ __launch_bounds__(256, 4) void k_h2m(const half8* __restrict__ h1,
                                                const half8* __restrict__ Btab8,
                                                const int* __restrict__ nbr_idx,
                                                const uint4* __restrict__ bits4,
                                                const float* __restrict__ w_out,
                                                float* __restrict__ outf,
                                                int n_total) {
    __shared__ int4 sB8[NS * 32];       // 10752 B compact Btab
    __shared__ int  sidx[4 * 1300];     // 4 waves x (1296 idx + pad) = 20800 B
    const int tid = threadIdx.x;
    const int lane = tid & 63, wid = tid >> 6;
    const int m = lane & 15, q = lane >> 4;

    const int rw = blockIdx.x * 64 + (wid << 4);       // wave's first row
    int wb = rw;
    if (wb + 16 > n_total) wb = n_total - 16;          // clamp (N%16==0)

    // stage wave's 16 idx rows: 5184 contiguous bytes = 324 int4
    {
        int4* dst = (int4*)(sidx + wid * 1300);
        const int4* gsrc = (const int4*)(nbr_idx + (size_t)wb * KK);
#pragma unroll
        for (int j = 0; j < 6; j++) {
            int li = lane + j * 64;
            if (li < 324) dst[li] = gsrc[li];
        }
    }
    // stage compact Btab8: 672 int4, block-wide
    {
        const int4* gB = (const int4*)Btab8;
#pragma unroll
        for (int j = 0; j < 3; j++) {
            int i = tid + j * 256;
            if (i < NS * 32) sB8[i] = gB[i];
        }
    }
    __syncthreads();

    const int rowc = wb + m;
    const uint4 bw = bits4[rowc];
    const int* mi = sidx + wid * 1300 + m * KK + q;    // [4s] per slice

    f32x4 acc0 = {0.f, 0.f, 0.f, 0.f};
    f32x4 acc1 = {0.f, 0.f, 0.f, 0.f};
#pragma unroll
    for (int s = 0; s < NS; s++) {
        const unsigned word = (s < 8) ? bw.x : (s < 16) ? bw.y : bw.z;
        const unsigned bit = (word >> ((4 * s + q) & 31)) & 1u;
        // s==20, q>=1 reads pad garbage; bit==0 there (bits 81+ zero) so the
        // exec mask kills both the load and the contribution. No OOB: 1298<1300.
        const unsigned ixr = (unsigned)mi[4 * s];      // ds_read_b32, imm offset
        half8 a = {(_Float16)0.f, (_Float16)0.f, (_Float16)0.f, (_Float16)0.f,
                   (_Float16)0.f, (_Float16)0.f, (_Float16)0.f, (_Float16)0.f};
        if (bit) a = h1[ixr];                          // exec-masked 16 B gather
        half8 b = {(_Float16)0.f, (_Float16)0.f, (_Float16)0.f, (_Float16)0.f,
                   (_Float16)0.f, (_Float16)0.f, (_Float16)0.f, (_Float16)0.f};
        if (m < CH) b = *(const half8*)&sB8[s * 32 + q * 8 + m];  // ds_read_b128
        if (s & 1) acc1 = __builtin_amdgcn_mfma_f32_16x16x32_f16(a, b, acc1, 0, 0, 0);
        else       acc0 = __builtin_amdgcn_mfma_f32_16x16x32_f16(a, b, acc0, 0, 0, 0);
    }
    f32x4 acc = acc0 + acc1;

    // C/D layout: col = lane&15 (=channel m), row = q*4 + reg (=local out row).
    float wo = (m < CH) ? w_out[m] : 0.f;
    float v0 = fmaxf(acc[0], 0.f) * wo, v1 = fmaxf(acc[1], 0.f) * wo;
    float v2 = fmaxf(acc[2], 0.f) * wo, v3 = fmaxf(acc[3], 0.f) * wo;
#pragma unroll
    for (int off = 1; off < 16; off <<= 1) {
        v0 += __shfl_xor(v0, off, 16);
        v1 += __shfl_xor(v1, off, 16);
        v2 += __shfl_xor(v2, off, 16);
        v3 += __shfl_xor(v3, off, 16);
    }
    if (m == 0) {
        int gn = rw + q * 4;   // tail-wave rows (wb!=rw) -> gn >= n_total -> no-op
        if (gn + 0 < n_total) outf[gn + 0] = v0;
        if (gn + 1 < n_total) outf[gn + 1] = v1;
        if (gn + 2 < n_total) outf[gn + 2] = v2;
        if (gn + 3 < n_total) outf[gn + 3] = v3;
    }
}

// ---------------- deterministic dense scatter (write phase) -----------------
__global__ __launch_bounds__(256) void k_scat_write(const int* __restrict__ coords,
                                                    const int* __restrict__ batch,
                                                    const float* __restrict__ outf,
                                                    int* dsti, float* dstf, int n_total) {
    int n = blockIdx.x * blockDim.x + threadIdx.x;
    if (n >= n_total) return;
    int cell = cell_of(coords, batch, n);
    if (dsti[cell] == n + 1) dstf[cell] = outf[n];
}

extern "C" void kernel_launch(void* const* d_in, const int* in_sizes, int n_in,
                              void* d_out, int out_size, void* d_ws, size_t ws_size,
                              hipStream_t stream) {
    const float* w1       = (const float*)d_in[1];
    const float* w2       = (const float*)d_in[2];
    const float* w_out    = (const float*)d_in[3];
    const int*   nbr_idx  = (const int*)d_in[4];
    const int*   nbr_mask = (const int*)d_in[5];
    const int*   coords   = (const int*)d_in[6];
    const int*   batch    = (const int*)d_in[7];

    int n_total = in_sizes[0];

    // ws: h1 (N+1 fp16x8) | bits4 (N uint4) | outf (N f32) | Btab8 | W1tab
    half8* h1    = (half8*)d_ws;
    uint4* bits4 = (uint4*)((char*)d_ws + (size_t)(n_total + 1) * sizeof(half8));
    float* outf  = (float*)((char*)bits4 + (size_t)n_total * sizeof(uint4));
    half8* Btab8 = (half8*)(outf + n_total);
    half8* W1tab = Btab8 + NS * 32;
    float* out   = (float*)d_out;

    int n4 = out_size / 4;   // 16,777,216 floats -> 4,194,304 float4
    k_zero<<<2048, 256, 0, stream>>>((float4*)out, n4, w1, W1tab, h1, n_total);

    int nb1 = (n_total + 63) / 64;
    k_h1b<<<nb1, 256, 0, stream>>>(W1tab, w2, nbr_mask, coords, batch,
                                   h1, bits4, Btab8, (int*)out, n_total);
    k_h2m<<<nb1, 256, 0, stream>>>(h1, Btab8, nbr_idx, bits4, w_out, outf, n_total);
    int nb = (n_total + 255) / 256;
    k_scat_write<<<nb, 256, 0, stream>>>(coords, batch, outf, (int*)out, out, n_total);
}